// Round 1
// baseline (2056.608 us; speedup 1.0000x reference)
//
#include <hip/hip_runtime.h>
#include <math.h>

#define B_   128
#define L_   197
#define C_   768
#define Nv_  196
#define Lt_  32
#define Ct_  512
#define H_   12
#define DH_  64
#define DPP_ 256
#define MTOK 25088   // B_*Nv_

// ---------------------------------------------------------------------------
// Generic fp32 NT GEMM: C[m][n] = scale * sum_k A[m][k]*B[n][k] (+ bias[n])
// GATHER_A: A row m -> vis_tok row: x[((n+1)*B + b)*C + k], m = b*196+n
// BOUNDS:   guard M/N edges (gram 196x196)
// EPI==1:   MLP epilogue: gelu(h)=h*sigmoid(1.702h), partial dots with W2
//           -> partials[m][6][2] (deterministic, no atomics)
// ---------------------------------------------------------------------------
template<int GATHER_A, int BOUNDS, int EPI>
__global__ __launch_bounds__(256)
void gemm_nt(const float* __restrict__ A, const float* __restrict__ Bm,
             const float* __restrict__ bias, float* __restrict__ C,
             int M, int N, int K, float scale,
             long strideA, long strideC,
             const float* __restrict__ W2, float* __restrict__ partials)
{
    __shared__ float As[16][132];
    __shared__ float Bs[16][132];
    const int tid = threadIdx.x;
    const int tx = tid & 15, ty = tid >> 4;
    const int m0 = blockIdx.x * 128, n0 = blockIdx.y * 128;
    const int bz = blockIdx.z;
    const float* Ab = A  + (size_t)bz * strideA;
    const float* Bb = Bm + (size_t)bz * strideA;
    float* Cb = C + (size_t)bz * strideC;

    float acc[8][8];
#pragma unroll
    for (int r = 0; r < 8; ++r)
#pragma unroll
        for (int c = 0; c < 8; ++c) acc[r][c] = 0.f;

    for (int k0 = 0; k0 < K; k0 += 16) {
#pragma unroll
        for (int Lq = 0; Lq < 2; ++Lq) {
            int idx = tid + Lq * 256;
            int row = idx >> 2;
            int kq  = (idx & 3) << 2;
            { // A tile
                int gr = m0 + row;
                float4 v = make_float4(0.f, 0.f, 0.f, 0.f);
                if (!BOUNDS || gr < M) {
                    const float* src;
                    if (GATHER_A) {
                        int b = gr / Nv_, n = gr - b * Nv_;
                        src = A + ((size_t)(n + 1) * B_ + b) * C_ + k0 + kq;
                    } else {
                        src = Ab + (size_t)gr * K + k0 + kq;
                    }
                    v = *(const float4*)src;
                }
                As[kq + 0][row] = v.x; As[kq + 1][row] = v.y;
                As[kq + 2][row] = v.z; As[kq + 3][row] = v.w;
            }
            { // B tile
                int gc = n0 + row;
                float4 v = make_float4(0.f, 0.f, 0.f, 0.f);
                if (!BOUNDS || gc < N)
                    v = *(const float4*)(Bb + (size_t)gc * K + k0 + kq);
                Bs[kq + 0][row] = v.x; Bs[kq + 1][row] = v.y;
                Bs[kq + 2][row] = v.z; Bs[kq + 3][row] = v.w;
            }
        }
        __syncthreads();
#pragma unroll
        for (int kk = 0; kk < 16; ++kk) {
            float a[8], b[8];
            *(float4*)&a[0] = *(const float4*)&As[kk][ty * 8];
            *(float4*)&a[4] = *(const float4*)&As[kk][ty * 8 + 4];
            *(float4*)&b[0] = *(const float4*)&Bs[kk][tx * 8];
            *(float4*)&b[4] = *(const float4*)&Bs[kk][tx * 8 + 4];
#pragma unroll
            for (int r = 0; r < 8; ++r)
#pragma unroll
                for (int c = 0; c < 8; ++c)
                    acc[r][c] = fmaf(a[r], b[c], acc[r][c]);
        }
        __syncthreads();
    }

    if constexpr (EPI == 0) {
#pragma unroll
        for (int r = 0; r < 8; ++r) {
            int gr = m0 + ty * 8 + r;
            if (BOUNDS && gr >= M) continue;
#pragma unroll
            for (int c = 0; c < 8; ++c) {
                int gc = n0 + tx * 8 + c;
                if (BOUNDS && gc >= N) continue;
                float v = acc[r][c] * scale;
                if (bias) v += bias[gc];
                Cb[(size_t)gr * N + gc] = v;
            }
        }
    } else {
        // MLP epilogue: gelu then per-thread partial dot with W2 rows
        float p0[8], p1[8];
#pragma unroll
        for (int r = 0; r < 8; ++r) { p0[r] = 0.f; p1[r] = 0.f; }
#pragma unroll
        for (int c = 0; c < 8; ++c) {
            int gc = n0 + tx * 8 + c;
            float w20 = W2[gc], w21 = W2[C_ + gc];
            float b1v = bias[gc];
#pragma unroll
            for (int r = 0; r < 8; ++r) {
                float h  = acc[r][c] + b1v;
                float gl = h / (1.f + expf(-1.702f * h));
                p0[r] = fmaf(gl, w20, p0[r]);
                p1[r] = fmaf(gl, w21, p1[r]);
            }
        }
#pragma unroll
        for (int off = 8; off; off >>= 1) {
#pragma unroll
            for (int r = 0; r < 8; ++r) {
                p0[r] += __shfl_xor(p0[r], off, 16);
                p1[r] += __shfl_xor(p1[r], off, 16);
            }
        }
        if (tx == 0) {
#pragma unroll
            for (int r = 0; r < 8; ++r) {
                int gr = m0 + ty * 8 + r;
                partials[(size_t)gr * 12 + blockIdx.y * 2 + 0] = p0[r];
                partials[(size_t)gr * 12 + blockIdx.y * 2 + 1] = p1[r];
            }
        }
    }
}

// ---------------------------------------------------------------------------
// Attention per (b,h): scores=qK^T/8, softmax over 32, ctx=attn@V,
// fused = ctx + vis_tok written IN-PLACE over q (safe: each WG owns its slice,
// row read happens before its write within the same iteration).
// ---------------------------------------------------------------------------
__global__ __launch_bounds__(256)
void attn_kernel(const float* __restrict__ q, const float* __restrict__ k,
                 const float* __restrict__ v, const float* __restrict__ x,
                 float* __restrict__ fused)
{
    __shared__ float Ks[Lt_][DH_ + 1];
    __shared__ float Vs[Lt_][DH_ + 1];
    __shared__ float qs[4][DH_];
    __shared__ float as[4][Lt_];
    const int bh = blockIdx.x;
    const int b = bh / H_, h = bh - b * H_;
    const int tid = threadIdx.x;
    const int wv = tid >> 6, lane = tid & 63;

    for (int idx = tid; idx < Lt_ * 16; idx += 256) {  // 512 float4
        int l = idx >> 4, dq = (idx & 15) << 2;
        size_t off = ((size_t)(b * Lt_ + l)) * C_ + h * DH_ + dq;
        float4 kv4 = *(const float4*)(k + off);
        Ks[l][dq] = kv4.x; Ks[l][dq + 1] = kv4.y; Ks[l][dq + 2] = kv4.z; Ks[l][dq + 3] = kv4.w;
        float4 vv4 = *(const float4*)(v + off);
        Vs[l][dq] = vv4.x; Vs[l][dq + 1] = vv4.y; Vs[l][dq + 2] = vv4.z; Vs[l][dq + 3] = vv4.w;
    }
    __syncthreads();

    for (int it = 0; it < 49; ++it) {
        int n = it * 4 + wv;   // always < 196
        size_t qoff = ((size_t)(b * Nv_ + n)) * C_ + h * DH_ + lane;
        float qv = q[qoff];
        qs[wv][lane] = qv;
        __syncthreads();
        float s;
        if (lane < Lt_) {
            s = 0.f;
#pragma unroll
            for (int d = 0; d < DH_; ++d) s = fmaf(qs[wv][d], Ks[lane][d], s);
            s *= 0.125f;
        } else s = -1e30f;
        float mx = s;
#pragma unroll
        for (int off = 16; off; off >>= 1) mx = fmaxf(mx, __shfl_xor(mx, off, 32));
        float p = (lane < Lt_) ? expf(s - mx) : 0.f;
        float sum = p;
#pragma unroll
        for (int off = 16; off; off >>= 1) sum += __shfl_xor(sum, off, 32);
        if (lane < Lt_) as[wv][lane] = p / sum;
        __syncthreads();
        float c = 0.f;
#pragma unroll
        for (int l = 0; l < Lt_; ++l) c = fmaf(as[wv][l], Vs[l][lane], c);
        float xv = x[((size_t)(n + 1) * B_ + b) * C_ + h * DH_ + lane];
        fused[qoff] = c + xv;
    }
}

// ---------------------------------------------------------------------------
// keep decisions: logits from partials (+b2), gumbel, policy bits, keep_prob
// ---------------------------------------------------------------------------
__global__ __launch_bounds__(256)
void keep_kernel(const float* __restrict__ partials, const float* __restrict__ b2,
                 const float* __restrict__ gumbel, float* __restrict__ policy,
                 float* __restrict__ keep_prob)
{
    int m = blockIdx.x * 256 + threadIdx.x;   // < 25088 exactly
    int b = m / Nv_, n = m - b * Nv_;
    float l0 = b2[0], l1 = b2[1];
#pragma unroll
    for (int t = 0; t < 6; ++t) {
        l0 += partials[(size_t)m * 12 + t * 2 + 0];
        l1 += partials[(size_t)m * 12 + t * 2 + 1];
    }
    const float UHI = (float)(1.0 - 1e-6);
    float U0 = fminf(fmaxf(gumbel[(size_t)m * 2 + 0], 1e-6f), UHI);
    float U1 = fminf(fmaxf(gumbel[(size_t)m * 2 + 1], 1e-6f), UHI);
    // match numpy f32 pipeline: each log correctly rounded to f32
    float t0 = (float)log((double)U0);
    float g0 = -(float)log((double)(-t0));
    float t1 = (float)log((double)U1);
    float g1 = -(float)log((double)(-t1));
    float dlog = (l1 + g1) - (l0 + g0);
    float kp = 1.f / (1.f + expf(-dlog));
    policy[(size_t)b * 197 + 1 + n] = (dlog > 0.f) ? 1.f : 0.f;
    if (n == 0) policy[(size_t)b * 197] = 1.f;
    keep_prob[m] = kp;
}

// deterministic per-batch keep_prob sum
__global__ __launch_bounds__(256)
void batch_reduce(const float* __restrict__ keep_prob, float* __restrict__ sum_kp)
{
    __shared__ float part[4];
    int b = blockIdx.x, tid = threadIdx.x;
    float vs = (tid < Nv_) ? keep_prob[(size_t)b * Nv_ + tid] : 0.f;
#pragma unroll
    for (int off = 32; off; off >>= 1) vs += __shfl_xor(vs, off, 64);
    if ((tid & 63) == 0) part[tid >> 6] = vs;
    __syncthreads();
    if (tid == 0) sum_kp[b] = part[0] + part[1] + part[2] + part[3];
}

// phi row-normalize * sqrt(max(kp/(mean kp+eps),1e-6)), in place (rel==1)
__global__ __launch_bounds__(256)
void pw_scale(float* __restrict__ phi, const float* __restrict__ keep_prob,
              const float* __restrict__ sum_kp)
{
    int m = blockIdx.x * 4 + (threadIdx.x >> 6);
    int lane = threadIdx.x & 63;
    float4* row = (float4*)phi + (size_t)m * 64;
    float4 vv = row[lane];
    float ss = vv.x * vv.x + vv.y * vv.y + vv.z * vv.z + vv.w * vv.w;
#pragma unroll
    for (int off = 32; off; off >>= 1) ss += __shfl_xor(ss, off, 64);
    float nrm = fmaxf(sqrtf(ss), 1e-12f);
    int b = m / Nv_;
    float kp = keep_prob[m];
    float meanw = sum_kp[b] * (1.f / 196.f);
    float wn = fmaxf(kp / (meanw + 1e-12f), 1e-6f);
    float sc = sqrtf(wn) / nrm;
    vv.x *= sc; vv.y *= sc; vv.z *= sc; vv.w *= sc;
    row[lane] = vv;
}

// ---------------------------------------------------------------------------
// Per-batch Cholesky logdet. Packed lower triangle in dynamic LDS (78 KB).
// A = G + (1+1e-5) I ; logdet_b = sum_j log(pivot_j)
// ---------------------------------------------------------------------------
__global__ __launch_bounds__(256)
void chol_kernel(const float* __restrict__ G, float* __restrict__ logdet_arr)
{
    extern __shared__ float sm[];
    float* Ls  = sm;            // 19306 = 196*197/2
    float* col = sm + 19306;    // 196
    const int b = blockIdx.x, tid = threadIdx.x;
    const float* Gb = G + (size_t)b * Nv_ * Nv_;

    for (int i = 0; i < Nv_; ++i) {
        int base = (i * (i + 1)) >> 1;
        for (int kk = tid; kk <= i; kk += 256) {
            float vv = Gb[(size_t)i * Nv_ + kk];
            if (kk == i) vv += 1.00001f;   // 1 + DPP_EPS
            Ls[base + kk] = vv;
        }
    }
    __syncthreads();

    float acc = 0.f;
    const int tx = tid & 15, tg = tid >> 4;
    for (int j = 0; j < Nv_; ++j) {
        float piv = Ls[((j * (j + 1)) >> 1) + j];
        if (tid == 0) acc += logf(piv);
        float inv = 1.f / sqrtf(piv);
        for (int i = j + 1 + tid; i < Nv_; i += 256) {
            float vv = Ls[((i * (i + 1)) >> 1) + j] * inv;
            Ls[((i * (i + 1)) >> 1) + j] = vv;
            col[i] = vv;
        }
        __syncthreads();
        for (int i0 = j + 1 + tg * 4; i0 < Nv_; i0 += 64) {
            float Li[4]; int basei[4];
#pragma unroll
            for (int r = 0; r < 4; ++r) {
                int i = i0 + r;
                Li[r] = (i < Nv_) ? col[i] : 0.f;
                basei[r] = (i < Nv_) ? ((i * (i + 1)) >> 1) : 0;
            }
            int kmax = i0 + 3; if (kmax > Nv_ - 1) kmax = Nv_ - 1;
            for (int kk = j + 1 + tx; kk <= kmax; kk += 16) {
                float ck = col[kk];
#pragma unroll
                for (int r = 0; r < 4; ++r) {
                    int i = i0 + r;
                    if (i < Nv_ && kk <= i)
                        Ls[basei[r] + kk] -= Li[r] * ck;
                }
            }
        }
        __syncthreads();
    }
    if (tid == 0) logdet_arr[b] = acc;
}

// deterministic serial finalize
__global__ void finalize_kernel(const float* __restrict__ sum_kp,
                                const float* __restrict__ logdet_arr,
                                float* __restrict__ out)
{
    float tot = 0.f, ld = 0.f;
    for (int b = 0; b < B_; ++b) { tot += sum_kp[b]; ld += logdet_arr[b]; }
    float mean = tot * (1.f / 25088.f);
    float d = mean - 0.7f;
    out[25216] = d * d;
    out[25217] = -ld * (1.f / 128.f);
}

// ---------------------------------------------------------------------------
extern "C" void kernel_launch(void* const* d_in, const int* in_sizes, int n_in,
                              void* d_out, int out_size, void* d_ws, size_t ws_size,
                              hipStream_t stream)
{
    const float* x      = (const float*)d_in[0];
    const float* text   = (const float*)d_in[1];
    const float* gumbel = (const float*)d_in[2];
    const float* Wq     = (const float*)d_in[3];
    const float* bq     = (const float*)d_in[4];
    const float* Wk     = (const float*)d_in[5];
    const float* bk     = (const float*)d_in[6];
    const float* Wv     = (const float*)d_in[7];
    const float* bv     = (const float*)d_in[8];
    const float* W1     = (const float*)d_in[9];
    const float* b1     = (const float*)d_in[10];
    const float* W2     = (const float*)d_in[11];
    const float* b2     = (const float*)d_in[12];
    const float* Wdpp   = (const float*)d_in[13];
    float* out = (float*)d_out;

    // workspace layout (floats); q/fused buffer reused for G after MLP.
    float* ws = (float*)d_ws;
    float* q          = ws;                       // 25088*768 = 19,267,584
    float* kbuf       = q + 19267584;             //  4096*768 =  3,145,728
    float* vbuf       = kbuf + 3145728;           //  3,145,728
    float* phi        = vbuf + 3145728;           // 25088*256 =  6,422,528
    float* partials   = phi + 6422528;            // 25088*12  =    301,056
    float* keep_prob  = partials + 301056;        //     25,088
    float* sum_kp     = keep_prob + 25088;        //        128
    float* logdet_arr = sum_kp + 128;             //        128
    float* G          = ws;                       // reuse q region (dead after MLP)

    dim3 blk(256);

    // k,v projections: M=4096, N=768, K=512
    gemm_nt<0,0,0><<<dim3(32,6,1), blk, 0, stream>>>(text, Wk, bk, kbuf, 4096, 768, 512, 1.f, 0, 0, nullptr, nullptr);
    gemm_nt<0,0,0><<<dim3(32,6,1), blk, 0, stream>>>(text, Wv, bv, vbuf, 4096, 768, 512, 1.f, 0, 0, nullptr, nullptr);
    // q projection (gathered vis_tok): M=25088, N=768, K=768
    gemm_nt<1,0,0><<<dim3(196,6,1), blk, 0, stream>>>(x, Wq, bq, q, MTOK, 768, 768, 1.f, 0, 0, nullptr, nullptr);
    // attention + residual -> fused (in place over q)
    attn_kernel<<<dim3(B_*H_), blk, 0, stream>>>(q, kbuf, vbuf, x, q);
    // MLP: hmid=gelu(fused@W1^T+b1); partial logits via W2 in epilogue
    gemm_nt<0,0,1><<<dim3(196,6,1), blk, 0, stream>>>(q, W1, b1, nullptr, MTOK, 768, 768, 1.f, 0, 0, W2, partials);
    // keep decisions + policy
    keep_kernel<<<dim3(98), blk, 0, stream>>>(partials, b2, gumbel, out, keep_prob);
    batch_reduce<<<dim3(B_), blk, 0, stream>>>(keep_prob, sum_kp);
    // phi projection (gathered vis_tok): M=25088, N=256, K=768
    gemm_nt<1,0,0><<<dim3(196,2,1), blk, 0, stream>>>(x, Wdpp, nullptr, phi, MTOK, 256, 768, 1.f, 0, 0, nullptr, nullptr);
    // normalize + weight -> pw (in place)
    pw_scale<<<dim3(6272), blk, 0, stream>>>(phi, keep_prob, sum_kp);
    // per-batch gram: G = pw@pw^T / (DPP*Nv*DPP_TAU)
    gemm_nt<0,1,0><<<dim3(2,2,B_), blk, 0, stream>>>(phi, phi, nullptr, G, Nv_, Nv_, 256,
                                                     1.0f/(256.0f*196.0f*0.01f),
                                                     (long)Nv_*256, (long)Nv_*Nv_, nullptr, nullptr);
    // per-batch Cholesky logdet
    size_t shb = (size_t)(19306 + 196) * sizeof(float);
    (void)hipFuncSetAttribute((const void*)chol_kernel,
                              hipFuncAttributeMaxDynamicSharedMemorySize, (int)shb);
    chol_kernel<<<dim3(B_), blk, shb, stream>>>(G, logdet_arr);
    // scalars
    finalize_kernel<<<dim3(1), dim3(1), 0, stream>>>(sum_kp, logdet_arr, out);
}

// Round 3
// 1558.977 us; speedup vs baseline: 1.3192x; 1.3192x over previous
//
#include <hip/hip_runtime.h>
#include <math.h>

#define B_   128
#define L_   197
#define C_   768
#define Nv_  196
#define Lt_  32
#define Ct_  512
#define H_   12
#define DH_  64
#define DPP_ 256
#define MTOK 25088   // B_*Nv_

// ---------------------------------------------------------------------------
// Generic fp32 NT GEMM: C[m][n] = scale * sum_k A[m][k]*B[n][k] (+ bias[n])
// GATHER_A: A row m -> vis_tok row: x[((n+1)*B + b)*C + k], m = b*196+n
// BOUNDS:   guard M/N edges (gram 196x196)
// EPI==1:   MLP epilogue: gelu(h)=h*sigmoid(1.702h), partial dots with W2
//           -> partials[m][6][2] (deterministic, no atomics)
// ---------------------------------------------------------------------------
template<int GATHER_A, int BOUNDS, int EPI>
__global__ __launch_bounds__(256)
void gemm_nt(const float* __restrict__ A, const float* __restrict__ Bm,
             const float* __restrict__ bias, float* __restrict__ C,
             int M, int N, int K, float scale,
             long strideA, long strideC,
             const float* __restrict__ W2, float* __restrict__ partials)
{
    __shared__ float As[16][132];
    __shared__ float Bs[16][132];
    const int tid = threadIdx.x;
    const int tx = tid & 15, ty = tid >> 4;
    const int m0 = blockIdx.x * 128, n0 = blockIdx.y * 128;
    const int bz = blockIdx.z;
    const float* Ab = A  + (size_t)bz * strideA;
    const float* Bb = Bm + (size_t)bz * strideA;
    float* Cb = C + (size_t)bz * strideC;

    float acc[8][8];
#pragma unroll
    for (int r = 0; r < 8; ++r)
#pragma unroll
        for (int c = 0; c < 8; ++c) acc[r][c] = 0.f;

    for (int k0 = 0; k0 < K; k0 += 16) {
#pragma unroll
        for (int Lq = 0; Lq < 2; ++Lq) {
            int idx = tid + Lq * 256;
            int row = idx >> 2;
            int kq  = (idx & 3) << 2;
            { // A tile
                int gr = m0 + row;
                float4 v = make_float4(0.f, 0.f, 0.f, 0.f);
                if (!BOUNDS || gr < M) {
                    const float* src;
                    if (GATHER_A) {
                        int b = gr / Nv_, n = gr - b * Nv_;
                        src = A + ((size_t)(n + 1) * B_ + b) * C_ + k0 + kq;
                    } else {
                        src = Ab + (size_t)gr * K + k0 + kq;
                    }
                    v = *(const float4*)src;
                }
                As[kq + 0][row] = v.x; As[kq + 1][row] = v.y;
                As[kq + 2][row] = v.z; As[kq + 3][row] = v.w;
            }
            { // B tile
                int gc = n0 + row;
                float4 v = make_float4(0.f, 0.f, 0.f, 0.f);
                if (!BOUNDS || gc < N)
                    v = *(const float4*)(Bb + (size_t)gc * K + k0 + kq);
                Bs[kq + 0][row] = v.x; Bs[kq + 1][row] = v.y;
                Bs[kq + 2][row] = v.z; Bs[kq + 3][row] = v.w;
            }
        }
        __syncthreads();
#pragma unroll
        for (int kk = 0; kk < 16; ++kk) {
            float a[8], b[8];
            *(float4*)&a[0] = *(const float4*)&As[kk][ty * 8];
            *(float4*)&a[4] = *(const float4*)&As[kk][ty * 8 + 4];
            *(float4*)&b[0] = *(const float4*)&Bs[kk][tx * 8];
            *(float4*)&b[4] = *(const float4*)&Bs[kk][tx * 8 + 4];
#pragma unroll
            for (int r = 0; r < 8; ++r)
#pragma unroll
                for (int c = 0; c < 8; ++c)
                    acc[r][c] = fmaf(a[r], b[c], acc[r][c]);
        }
        __syncthreads();
    }

    if constexpr (EPI == 0) {
#pragma unroll
        for (int r = 0; r < 8; ++r) {
            int gr = m0 + ty * 8 + r;
            if (BOUNDS && gr >= M) continue;
#pragma unroll
            for (int c = 0; c < 8; ++c) {
                int gc = n0 + tx * 8 + c;
                if (BOUNDS && gc >= N) continue;
                float v = acc[r][c] * scale;
                if (bias) v += bias[gc];
                Cb[(size_t)gr * N + gc] = v;
            }
        }
    } else {
        // MLP epilogue: gelu then per-thread partial dot with W2 rows
        float p0[8], p1[8];
#pragma unroll
        for (int r = 0; r < 8; ++r) { p0[r] = 0.f; p1[r] = 0.f; }
#pragma unroll
        for (int c = 0; c < 8; ++c) {
            int gc = n0 + tx * 8 + c;
            float w20 = W2[gc], w21 = W2[C_ + gc];
            float b1v = bias[gc];
#pragma unroll
            for (int r = 0; r < 8; ++r) {
                float h  = acc[r][c] + b1v;
                float gl = h / (1.f + expf(-1.702f * h));
                p0[r] = fmaf(gl, w20, p0[r]);
                p1[r] = fmaf(gl, w21, p1[r]);
            }
        }
#pragma unroll
        for (int off = 8; off; off >>= 1) {
#pragma unroll
            for (int r = 0; r < 8; ++r) {
                p0[r] += __shfl_xor(p0[r], off, 16);
                p1[r] += __shfl_xor(p1[r], off, 16);
            }
        }
        if (tx == 0) {
#pragma unroll
            for (int r = 0; r < 8; ++r) {
                int gr = m0 + ty * 8 + r;
                partials[(size_t)gr * 12 + blockIdx.y * 2 + 0] = p0[r];
                partials[(size_t)gr * 12 + blockIdx.y * 2 + 1] = p1[r];
            }
        }
    }
}

// ---------------------------------------------------------------------------
// Attention per (b,h): scores=qK^T/8, softmax over 32, ctx=attn@V,
// fused = ctx + vis_tok written IN-PLACE over q.
// ---------------------------------------------------------------------------
__global__ __launch_bounds__(256)
void attn_kernel(const float* __restrict__ q, const float* __restrict__ k,
                 const float* __restrict__ v, const float* __restrict__ x,
                 float* __restrict__ fused)
{
    __shared__ float Ks[Lt_][DH_ + 1];
    __shared__ float Vs[Lt_][DH_ + 1];
    __shared__ float qs[4][DH_];
    __shared__ float as[4][Lt_];
    const int bh = blockIdx.x;
    const int b = bh / H_, h = bh - b * H_;
    const int tid = threadIdx.x;
    const int wv = tid >> 6, lane = tid & 63;

    for (int idx = tid; idx < Lt_ * 16; idx += 256) {  // 512 float4
        int l = idx >> 4, dq = (idx & 15) << 2;
        size_t off = ((size_t)(b * Lt_ + l)) * C_ + h * DH_ + dq;
        float4 kv4 = *(const float4*)(k + off);
        Ks[l][dq] = kv4.x; Ks[l][dq + 1] = kv4.y; Ks[l][dq + 2] = kv4.z; Ks[l][dq + 3] = kv4.w;
        float4 vv4 = *(const float4*)(v + off);
        Vs[l][dq] = vv4.x; Vs[l][dq + 1] = vv4.y; Vs[l][dq + 2] = vv4.z; Vs[l][dq + 3] = vv4.w;
    }
    __syncthreads();

    for (int it = 0; it < 49; ++it) {
        int n = it * 4 + wv;   // always < 196
        size_t qoff = ((size_t)(b * Nv_ + n)) * C_ + h * DH_ + lane;
        float qv = q[qoff];
        qs[wv][lane] = qv;
        __syncthreads();
        float s;
        if (lane < Lt_) {
            s = 0.f;
#pragma unroll
            for (int d = 0; d < DH_; ++d) s = fmaf(qs[wv][d], Ks[lane][d], s);
            s *= 0.125f;
        } else s = -1e30f;
        float mx = s;
#pragma unroll
        for (int off = 16; off; off >>= 1) mx = fmaxf(mx, __shfl_xor(mx, off, 32));
        float p = (lane < Lt_) ? expf(s - mx) : 0.f;
        float sum = p;
#pragma unroll
        for (int off = 16; off; off >>= 1) sum += __shfl_xor(sum, off, 32);
        if (lane < Lt_) as[wv][lane] = p / sum;
        __syncthreads();
        float c = 0.f;
#pragma unroll
        for (int l = 0; l < Lt_; ++l) c = fmaf(as[wv][l], Vs[l][lane], c);
        float xv = x[((size_t)(n + 1) * B_ + b) * C_ + h * DH_ + lane];
        fused[qoff] = c + xv;
    }
}

// ---------------------------------------------------------------------------
// keep decisions: logits from partials (+b2), gumbel, policy bits, keep_prob
// ---------------------------------------------------------------------------
__global__ __launch_bounds__(256)
void keep_kernel(const float* __restrict__ partials, const float* __restrict__ b2,
                 const float* __restrict__ gumbel, float* __restrict__ policy,
                 float* __restrict__ keep_prob)
{
    int m = blockIdx.x * 256 + threadIdx.x;   // < 25088 exactly
    int b = m / Nv_, n = m - b * Nv_;
    float l0 = b2[0], l1 = b2[1];
#pragma unroll
    for (int t = 0; t < 6; ++t) {
        l0 += partials[(size_t)m * 12 + t * 2 + 0];
        l1 += partials[(size_t)m * 12 + t * 2 + 1];
    }
    const float UHI = (float)(1.0 - 1e-6);
    float U0 = fminf(fmaxf(gumbel[(size_t)m * 2 + 0], 1e-6f), UHI);
    float U1 = fminf(fmaxf(gumbel[(size_t)m * 2 + 1], 1e-6f), UHI);
    float t0 = (float)log((double)U0);
    float g0 = -(float)log((double)(-t0));
    float t1 = (float)log((double)U1);
    float g1 = -(float)log((double)(-t1));
    float dlog = (l1 + g1) - (l0 + g0);
    float kp = 1.f / (1.f + expf(-dlog));
    policy[(size_t)b * 197 + 1 + n] = (dlog > 0.f) ? 1.f : 0.f;
    if (n == 0) policy[(size_t)b * 197] = 1.f;
    keep_prob[m] = kp;
}

// deterministic per-batch keep_prob sum
__global__ __launch_bounds__(256)
void batch_reduce(const float* __restrict__ keep_prob, float* __restrict__ sum_kp)
{
    __shared__ float part[4];
    int b = blockIdx.x, tid = threadIdx.x;
    float vs = (tid < Nv_) ? keep_prob[(size_t)b * Nv_ + tid] : 0.f;
#pragma unroll
    for (int off = 32; off; off >>= 1) vs += __shfl_xor(vs, off, 64);
    if ((tid & 63) == 0) part[tid >> 6] = vs;
    __syncthreads();
    if (tid == 0) sum_kp[b] = part[0] + part[1] + part[2] + part[3];
}

// phi row-normalize * sqrt(max(kp/(mean kp+eps),1e-6)), in place (rel==1)
__global__ __launch_bounds__(256)
void pw_scale(float* __restrict__ phi, const float* __restrict__ keep_prob,
              const float* __restrict__ sum_kp)
{
    int m = blockIdx.x * 4 + (threadIdx.x >> 6);
    int lane = threadIdx.x & 63;
    float4* row = (float4*)phi + (size_t)m * 64;
    float4 vv = row[lane];
    float ss = vv.x * vv.x + vv.y * vv.y + vv.z * vv.z + vv.w * vv.w;
#pragma unroll
    for (int off = 32; off; off >>= 1) ss += __shfl_xor(ss, off, 64);
    float nrm = fmaxf(sqrtf(ss), 1e-12f);
    int b = m / Nv_;
    float kp = keep_prob[m];
    float meanw = sum_kp[b] * (1.f / 196.f);
    float wn = fmaxf(kp / (meanw + 1e-12f), 1e-6f);
    float sc = sqrtf(wn) / nrm;
    vv.x *= sc; vv.y *= sc; vv.z *= sc; vv.w *= sc;
    row[lane] = vv;
}

// ---------------------------------------------------------------------------
// Per-batch blocked Cholesky logdet.
// Full-square LDS, row stride LS=197 floats (>= 196 columns! 197 % 32 == 5,
// gcd(5,32)=1 -> column walks over consecutive rows cycle all 32 banks;
// SYRK Lk reads at 4-row stride are exactly 2-way (free, m136)).
// Panel width 14 (196 = 14*14, uniform panels, fully unrolled SYRK t-loop).
// A = G + (1+1e-5) I ; logdet_b = sum_j log(pivot_j)
// ---------------------------------------------------------------------------
#define LS_   197
#define PBS_  14

__global__ __launch_bounds__(256)
void chol_kernel(const float* __restrict__ G, float* __restrict__ logdet_arr)
{
    extern __shared__ float sm[];
    float* Am  = sm;                 // 196 * 197
    float* col = sm + 196 * LS_;     // 196
    const int b = blockIdx.x, tid = threadIdx.x;
    const float* Gb = G + (size_t)b * Nv_ * Nv_;

    // load full square (coalesced float4), add (1+eps) to diagonal on the fly
    for (int idx = tid; idx < Nv_ * 49; idx += 256) {
        int i = idx / 49, c4 = (idx - i * 49) * 4;
        float4 v = *(const float4*)(Gb + (size_t)i * Nv_ + c4);
        if (i >= c4 && i < c4 + 4) (&v.x)[i - c4] += 1.00001f;
        float* dst = Am + i * LS_ + c4;
        dst[0] = v.x; dst[1] = v.y; dst[2] = v.z; dst[3] = v.w;
    }
    __syncthreads();

    float acc = 0.f;                 // thread 0 accumulates log pivots
    const int tx = tid & 15, ty = tid >> 4;

    for (int p = 0; p < Nv_ / PBS_; ++p) {
        const int j0 = p * PBS_;
        // ---- panel factorization (cols j0..j0+13, all rows below) ----
        for (int jj = j0; jj < j0 + PBS_; ++jj) {
            float piv = Am[jj * LS_ + jj];
            if (tid == 0) acc += logf(piv);
            float inv = 1.f / sqrtf(piv);
            for (int i = jj + 1 + tid; i < Nv_; i += 256) {
                float v = Am[i * LS_ + jj] * inv;
                Am[i * LS_ + jj] = v;
                col[i] = v;
            }
            __syncthreads();
            for (int k = jj + 1; k < j0 + PBS_; ++k) {
                float ck = col[k];
                for (int i = k + tid; i < Nv_; i += 256)
                    Am[i * LS_ + k] = fmaf(-col[i], ck, Am[i * LS_ + k]);
            }
            __syncthreads();
        }
        // ---- trailing SYRK: A[i][k] -= sum_t L[i][j0+t]*L[k][j0+t] ----
        const int j1 = j0 + PBS_;
        if (j1 >= Nv_) break;
        const int s = Nv_ - j1;
        const int nb = (s + 63) >> 6;
        for (int rb = 0; rb < nb; ++rb)
            for (int cb = 0; cb <= rb; ++cb) {
                const int i0 = j1 + rb * 64;
                const int k0 = j1 + cb * 64;
                float accs[4][4];
#pragma unroll
                for (int r = 0; r < 4; ++r)
#pragma unroll
                    for (int c = 0; c < 4; ++c) accs[r][c] = 0.f;
                float Li[4][PBS_];
#pragma unroll
                for (int r = 0; r < 4; ++r) {
                    int i = i0 + ty + 16 * r; if (i > 195) i = 195;
#pragma unroll
                    for (int t = 0; t < PBS_; ++t) Li[r][t] = Am[i * LS_ + j0 + t];
                }
#pragma unroll
                for (int t = 0; t < PBS_; ++t) {
                    float Lk[4];
#pragma unroll
                    for (int c = 0; c < 4; ++c) {
                        int k = k0 + 4 * tx + c; if (k > 195) k = 195;
                        Lk[c] = Am[k * LS_ + j0 + t];
                    }
#pragma unroll
                    for (int r = 0; r < 4; ++r)
#pragma unroll
                        for (int c = 0; c < 4; ++c)
                            accs[r][c] = fmaf(Li[r][t], Lk[c], accs[r][c]);
                }
#pragma unroll
                for (int r = 0; r < 4; ++r) {
                    int i = i0 + ty + 16 * r;
                    if (i < Nv_) {
#pragma unroll
                        for (int c = 0; c < 4; ++c) {
                            int k = k0 + 4 * tx + c;
                            if (k < Nv_) Am[i * LS_ + k] -= accs[r][c];
                        }
                    }
                }
            }
        __syncthreads();
    }
    if (tid == 0) logdet_arr[b] = acc;
}

// deterministic serial finalize
__global__ void finalize_kernel(const float* __restrict__ sum_kp,
                                const float* __restrict__ logdet_arr,
                                float* __restrict__ out)
{
    float tot = 0.f, ld = 0.f;
    for (int b = 0; b < B_; ++b) { tot += sum_kp[b]; ld += logdet_arr[b]; }
    float mean = tot * (1.f / 25088.f);
    float d = mean - 0.7f;
    out[25216] = d * d;
    out[25217] = -ld * (1.f / 128.f);
}

// ---------------------------------------------------------------------------
extern "C" void kernel_launch(void* const* d_in, const int* in_sizes, int n_in,
                              void* d_out, int out_size, void* d_ws, size_t ws_size,
                              hipStream_t stream)
{
    const float* x      = (const float*)d_in[0];
    const float* text   = (const float*)d_in[1];
    const float* gumbel = (const float*)d_in[2];
    const float* Wq     = (const float*)d_in[3];
    const float* bq     = (const float*)d_in[4];
    const float* Wk     = (const float*)d_in[5];
    const float* bk     = (const float*)d_in[6];
    const float* Wv     = (const float*)d_in[7];
    const float* bv     = (const float*)d_in[8];
    const float* W1     = (const float*)d_in[9];
    const float* b1     = (const float*)d_in[10];
    const float* W2     = (const float*)d_in[11];
    const float* b2     = (const float*)d_in[12];
    const float* Wdpp   = (const float*)d_in[13];
    float* out = (float*)d_out;

    float* ws = (float*)d_ws;
    float* q          = ws;                       // 25088*768
    float* kbuf       = q + 19267584;
    float* vbuf       = kbuf + 3145728;
    float* phi        = vbuf + 3145728;
    float* partials   = phi + 6422528;
    float* keep_prob  = partials + 301056;
    float* sum_kp     = keep_prob + 25088;
    float* logdet_arr = sum_kp + 128;
    float* G          = ws;                       // reuse q region (dead after MLP)

    dim3 blk(256);

    gemm_nt<0,0,0><<<dim3(32,6,1), blk, 0, stream>>>(text, Wk, bk, kbuf, 4096, 768, 512, 1.f, 0, 0, nullptr, nullptr);
    gemm_nt<0,0,0><<<dim3(32,6,1), blk, 0, stream>>>(text, Wv, bv, vbuf, 4096, 768, 512, 1.f, 0, 0, nullptr, nullptr);
    gemm_nt<1,0,0><<<dim3(196,6,1), blk, 0, stream>>>(x, Wq, bq, q, MTOK, 768, 768, 1.f, 0, 0, nullptr, nullptr);
    attn_kernel<<<dim3(B_*H_), blk, 0, stream>>>(q, kbuf, vbuf, x, q);
    gemm_nt<0,0,1><<<dim3(196,6,1), blk, 0, stream>>>(q, W1, b1, nullptr, MTOK, 768, 768, 1.f, 0, 0, W2, partials);
    keep_kernel<<<dim3(98), blk, 0, stream>>>(partials, b2, gumbel, out, keep_prob);
    batch_reduce<<<dim3(B_), blk, 0, stream>>>(keep_prob, sum_kp);
    gemm_nt<1,0,0><<<dim3(196,2,1), blk, 0, stream>>>(x, Wdpp, nullptr, phi, MTOK, 256, 768, 1.f, 0, 0, nullptr, nullptr);
    pw_scale<<<dim3(6272), blk, 0, stream>>>(phi, keep_prob, sum_kp);
    gemm_nt<0,1,0><<<dim3(2,2,B_), blk, 0, stream>>>(phi, phi, nullptr, G, Nv_, Nv_, 256,
                                                     1.0f/(256.0f*196.0f*0.01f),
                                                     (long)Nv_*256, (long)Nv_*Nv_, nullptr, nullptr);
    size_t shb = (size_t)(Nv_ * LS_ + Nv_) * sizeof(float);
    (void)hipFuncSetAttribute((const void*)chol_kernel,
                              hipFuncAttributeMaxDynamicSharedMemorySize, (int)shb);
    chol_kernel<<<dim3(B_), blk, shb, stream>>>(G, logdet_arr);
    finalize_kernel<<<dim3(1), dim3(1), 0, stream>>>(sum_kp, logdet_arr, out);
}